// Round 7
// baseline (2989.210 us; speedup 1.0000x reference)
//
#include <hip/hip_runtime.h>
#include <math.h>

#define N_NODES   32768
#define N_GRAPHS  64
#define NPG       512
#define N_EDGES   524288
#define D         128
#define N_ETYPES  4
#define N_STEPS   8

// ---------------------------------------------------------------------------
// Edge-type transform: tm[t][n][k] = sum_d h[n][d] * W[t][d][k]   (+bias)
// block: 256 threads, tile = 64 nodes x 128 cols for one etype.
// W_t staged through LDS in K-tiles of 16 (read from L2 once per block).
// Register blocking 8 nodes x 4 cols per thread; h tile transposed in LDS.
// LDS: hsT 34816 B + wl 8192 B = 43 KB (safe under 64 KB).
// ---------------------------------------------------------------------------
#define EKT 16
__global__ __launch_bounds__(256) void k_edge_transform(
    const float* __restrict__ h, const float* __restrict__ W,
    const float* __restrict__ b, float* __restrict__ tm)
{
    __shared__ float hsT[128 * 68];      // [d][n], pad 68 (float4-aligned)
    __shared__ float wl[EKT * 128];      // W k-tile [dd][k]
    const int t   = blockIdx.y;
    const int n0  = blockIdx.x * 64;
    const int tid = threadIdx.x;

    // stage h tile transposed: hsT[d][n] = h[n0+n][d]
    #pragma unroll
    for (int it = 0; it < 32; ++it) {
        int idx = it * 256 + tid;
        int n = idx >> 7, d = idx & 127;
        hsT[d * 68 + n] = h[(size_t)(n0 + n) * D + d];
    }

    const int kq = tid & 31, k4 = kq * 4;   // 4 consecutive cols
    const int ng = tid >> 5;                // 8 nodes: ng*8 .. +7
    const int nB = ng * 8;

    float acc[8][4];
    #pragma unroll
    for (int i = 0; i < 8; ++i)
        #pragma unroll
        for (int j = 0; j < 4; ++j) acc[i][j] = 0.f;

    const float* Wt = W + (size_t)t * D * D;
    for (int kt = 0; kt < D; kt += EKT) {
        __syncthreads();                 // covers hsT staging on first iter
        // stage 16x128 W slice: 512 float4 / 256 threads = 2 each
        {
            const float4* src = (const float4*)(Wt + (size_t)kt * D);
            float4* dstL = (float4*)wl;
            dstL[tid]       = src[tid];
            dstL[256 + tid] = src[256 + tid];
        }
        __syncthreads();
        #pragma unroll
        for (int dd = 0; dd < EKT; ++dd) {
            const int d = kt + dd;
            float4 w  = *(const float4*)(&wl[dd * 128 + k4]);
            float4 h0 = *(const float4*)(&hsT[d * 68 + nB]);
            float4 h1 = *(const float4*)(&hsT[d * 68 + nB + 4]);
            float hv[8] = {h0.x, h0.y, h0.z, h0.w, h1.x, h1.y, h1.z, h1.w};
            #pragma unroll
            for (int i = 0; i < 8; ++i) {
                acc[i][0] += hv[i] * w.x;
                acc[i][1] += hv[i] * w.y;
                acc[i][2] += hv[i] * w.z;
                acc[i][3] += hv[i] * w.w;
            }
        }
    }

    float4 bias = *(const float4*)(b + t * D + k4);
    float* outp = tm + (size_t)t * N_NODES * D + (size_t)n0 * D;
    #pragma unroll
    for (int i = 0; i < 8; ++i) {
        int n = nB + i;
        float4 v = make_float4(acc[i][0] + bias.x, acc[i][1] + bias.y,
                               acc[i][2] + bias.z, acc[i][3] + bias.w);
        *(float4*)(outp + (size_t)n * D + k4) = v;
    }
}

// ---------------------------------------------------------------------------
// CSR build (once per launch): histogram -> scan -> scatter of (src|etype)
// ---------------------------------------------------------------------------
__global__ void k_hist(const int* __restrict__ dst, int* __restrict__ cnt)
{
    int e = blockIdx.x * blockDim.x + threadIdx.x;
    if (e < N_EDGES) atomicAdd(&cnt[dst[e]], 1);
}

__global__ __launch_bounds__(1024) void k_scan(
    const int* __restrict__ cnt, int* __restrict__ row_start, int* __restrict__ cursor)
{
    __shared__ int part[1024];
    const int t = threadIdx.x;
    const int base = t * 32;

    int local[32];
    int s = 0;
    #pragma unroll
    for (int j = 0; j < 32; ++j) { local[j] = cnt[base + j]; s += local[j]; }
    part[t] = s;
    __syncthreads();

    for (int off = 1; off < 1024; off <<= 1) {
        int v   = part[t];
        int add = (t >= off) ? part[t - off] : 0;
        __syncthreads();
        part[t] = v + add;
        __syncthreads();
    }
    int ex = (t == 0) ? 0 : part[t - 1];

    if (t == 0) row_start[0] = 0;
    int run = ex;
    #pragma unroll
    for (int j = 0; j < 32; ++j) {
        cursor[base + j] = run;
        run += local[j];
        row_start[base + j + 1] = run;
    }
}

__global__ void k_scatter(const int* __restrict__ src, const int* __restrict__ dst,
                          const int* __restrict__ et, int* __restrict__ cursor,
                          int* __restrict__ sorted_se)
{
    int e = blockIdx.x * blockDim.x + threadIdx.x;
    if (e < N_EDGES) {
        int p = atomicAdd(&cursor[dst[e]], 1);
        sorted_se[p] = src[e] | (et[e] << 15);
    }
}

// ---------------------------------------------------------------------------
// Gather: a[n][:] = sum over incoming edges of tm[etype][src][:]
// one 64-lane wave per node, float2 per lane
// ---------------------------------------------------------------------------
__global__ __launch_bounds__(256) void k_gather(
    const float* __restrict__ tm, const int* __restrict__ row_start,
    const int* __restrict__ sorted_se, float* __restrict__ a)
{
    const int node = blockIdx.x * 4 + (threadIdx.x >> 6);
    const int lane = threadIdx.x & 63;
    const int s0 = row_start[node], s1 = row_start[node + 1];

    float ax = 0.f, ay = 0.f;
    for (int j = s0; j < s1; ++j) {
        int se = sorted_se[j];
        int s = se & 32767, t = se >> 15;
        const float2* row = (const float2*)(tm + ((size_t)t * N_NODES + s) * D);
        float2 v = row[lane];
        ax += v.x; ay += v.y;
    }
    ((float2*)(a + (size_t)node * D))[lane] = make_float2(ax, ay);
}

// ---------------------------------------------------------------------------
// Weight transpose (once per launch): w[384][128] -> wT[128][384]
// ---------------------------------------------------------------------------
__global__ void k_transpose(const float* __restrict__ w, float* __restrict__ wT)
{
    int id = blockIdx.x * blockDim.x + threadIdx.x;
    int j = id >> 7, d = id & 127;
    wT[d * 384 + j] = w[id];
}

// ---------------------------------------------------------------------------
// Fused GRU cell: h = GRU(a, h)  (in-place, tile of 32 nodes per block)
// Weights staged through LDS in K-tiles of 8 (read from L2 once per block).
// Per thread: 4 nodes x (3 gates x 4 cols) x 2 matrices = 96 accumulators.
// LDS: aT+hT 36864 B + wl 24576 B = 61.4 KB.
// ---------------------------------------------------------------------------
#define GKT 8
__global__ __launch_bounds__(256) void k_gru(
    const float* __restrict__ a, float* __restrict__ h,
    const float* __restrict__ wihT, const float* __restrict__ whhT,
    const float* __restrict__ bih, const float* __restrict__ bhh)
{
    __shared__ float aT[128 * 36];           // [d][n], pad 36
    __shared__ float hT[128 * 36];
    __shared__ float wl[2][GKT * 384];       // current k-tile: [ih/hh][dd][j]
    const int n0  = blockIdx.x * 32;
    const int tid = threadIdx.x;

    #pragma unroll
    for (int it = 0; it < 16; ++it) {
        int idx = it * 256 + tid;
        int n = idx >> 7, d = idx & 127;
        aT[d * 36 + n] = a[(size_t)(n0 + n) * D + d];
        hT[d * 36 + n] = h[(size_t)(n0 + n) * D + d];
    }

    const int kq = tid & 31, k4 = kq * 4;
    const int ng = tid >> 5;          // 4 nodes: ng*4 .. +3
    const int nA = ng * 4;

    float gi[4][3][4], gh[4][3][4];
    #pragma unroll
    for (int g = 0; g < 3; ++g) {
        float4 bi = *(const float4*)(bih + g * D + k4);
        float4 bh = *(const float4*)(bhh + g * D + k4);
        float biv[4] = {bi.x, bi.y, bi.z, bi.w};
        float bhv[4] = {bh.x, bh.y, bh.z, bh.w};
        #pragma unroll
        for (int i = 0; i < 4; ++i)
            #pragma unroll
            for (int j = 0; j < 4; ++j) { gi[i][g][j] = biv[j]; gh[i][g][j] = bhv[j]; }
    }

    for (int kt = 0; kt < D; kt += GKT) {
        __syncthreads();                 // covers aT/hT staging on first iter
        // stage weight k-tile: 2 x 8x384 floats = 2 x 768 float4, 3 each/thread
        {
            const float4* s0 = (const float4*)(wihT + (size_t)kt * 384);
            const float4* s1 = (const float4*)(whhT + (size_t)kt * 384);
            float4* d0 = (float4*)wl[0];
            float4* d1 = (float4*)wl[1];
            #pragma unroll
            for (int i = 0; i < 3; ++i) {
                d0[i * 256 + tid] = s0[i * 256 + tid];
                d1[i * 256 + tid] = s1[i * 256 + tid];
            }
        }
        __syncthreads();
        #pragma unroll
        for (int dd = 0; dd < GKT; ++dd) {
            const int d = kt + dd;
            float4 av = *(const float4*)(&aT[d * 36 + nA]);
            float4 hv = *(const float4*)(&hT[d * 36 + nA]);
            float avv[4] = {av.x, av.y, av.z, av.w};
            float hvv[4] = {hv.x, hv.y, hv.z, hv.w};
            #pragma unroll
            for (int g = 0; g < 3; ++g) {
                float4 wi = *(const float4*)(&wl[0][dd * 384 + g * 128 + k4]);
                float4 wh = *(const float4*)(&wl[1][dd * 384 + g * 128 + k4]);
                float wiv[4] = {wi.x, wi.y, wi.z, wi.w};
                float whv[4] = {wh.x, wh.y, wh.z, wh.w};
                #pragma unroll
                for (int i = 0; i < 4; ++i)
                    #pragma unroll
                    for (int j = 0; j < 4; ++j) {
                        gi[i][g][j] += avv[i] * wiv[j];
                        gh[i][g][j] += hvv[i] * whv[j];
                    }
            }
        }
    }

    #pragma unroll
    for (int i = 0; i < 4; ++i) {
        int n = n0 + nA + i;
        float hnew[4];
        #pragma unroll
        for (int j = 0; j < 4; ++j) {
            float ir = gi[i][0][j], iz = gi[i][1][j], in_ = gi[i][2][j];
            float hr = gh[i][0][j], hz = gh[i][1][j], hn  = gh[i][2][j];
            float r = 1.f / (1.f + __expf(-(ir + hr)));
            float z = 1.f / (1.f + __expf(-(iz + hz)));
            float nx = in_ + r * hn;
            float nn = 2.f / (1.f + __expf(-2.f * nx)) - 1.f;   // tanh
            float ho = hT[(k4 + j) * 36 + nA + i];
            hnew[j] = (1.f - z) * nn + z * ho;
        }
        *(float4*)(h + (size_t)n * D + k4) = make_float4(hnew[0], hnew[1], hnew[2], hnew[3]);
    }
}

// ---------------------------------------------------------------------------
// Readout: out[g] = sigmoid( sum_nodes(h) . w_cls + b_cls )
// ---------------------------------------------------------------------------
__global__ __launch_bounds__(256) void k_readout(
    const float* __restrict__ h, const float* __restrict__ w_cls,
    const float* __restrict__ b_cls, float* __restrict__ out)
{
    __shared__ float sbuf[256];
    const int g = blockIdx.x;
    const int tid = threadIdx.x;
    const int k = tid & 127, half = tid >> 7;

    float s = 0.f;
    for (int r = half; r < NPG; r += 2)
        s += h[((size_t)g * NPG + r) * D + k];
    sbuf[tid] = s;
    __syncthreads();

    if (tid < 64) {
        int l = tid;
        float v = (sbuf[l]      + sbuf[l + 128]) * w_cls[l]
                + (sbuf[l + 64] + sbuf[l + 192]) * w_cls[l + 64];
        #pragma unroll
        for (int off = 32; off > 0; off >>= 1) v += __shfl_down(v, off);
        if (l == 0) out[g] = 1.f / (1.f + __expf(-(v + b_cls[0])));
    }
}

// ---------------------------------------------------------------------------
extern "C" void kernel_launch(void* const* d_in, const int* in_sizes, int n_in,
                              void* d_out, int out_size, void* d_ws, size_t ws_size,
                              hipStream_t stream)
{
    const float* feat   = (const float*)d_in[0];
    const float* W_edge = (const float*)d_in[1];
    const float* b_edge = (const float*)d_in[2];
    const float* w_ih   = (const float*)d_in[3];
    const float* w_hh   = (const float*)d_in[4];
    const float* b_ih   = (const float*)d_in[5];
    const float* b_hh   = (const float*)d_in[6];
    const float* w_cls  = (const float*)d_in[7];
    const float* b_cls  = (const float*)d_in[8];
    const int*   src    = (const int*)d_in[9];
    const int*   dst    = (const int*)d_in[10];
    const int*   et     = (const int*)d_in[11];
    float* out = (float*)d_out;

    char* ws = (char*)d_ws;
    size_t off = 0;
    auto alloc = [&](size_t bytes) -> void* {
        void* p = ws + off;
        off += (bytes + 255) & ~(size_t)255;
        return p;
    };

    float* h         = (float*)alloc((size_t)N_NODES * D * 4);
    float* a         = (float*)alloc((size_t)N_NODES * D * 4);
    float* tm        = (float*)alloc((size_t)N_ETYPES * N_NODES * D * 4);
    int*   cnt       = (int*)alloc((size_t)N_NODES * 4);
    int*   cursor    = (int*)alloc((size_t)N_NODES * 4);
    int*   row_start = (int*)alloc((size_t)(N_NODES + 1) * 4);
    int*   sorted_se = (int*)alloc((size_t)N_EDGES * 4);
    float* wihT      = (float*)alloc((size_t)384 * D * 4);
    float* whhT      = (float*)alloc((size_t)384 * D * 4);

    hipMemcpyAsync(h, feat, (size_t)N_NODES * D * 4, hipMemcpyDeviceToDevice, stream);

    hipMemsetAsync(cnt, 0, (size_t)N_NODES * 4, stream);
    k_hist<<<N_EDGES / 256, 256, 0, stream>>>(dst, cnt);
    k_scan<<<1, 1024, 0, stream>>>(cnt, row_start, cursor);
    k_scatter<<<N_EDGES / 256, 256, 0, stream>>>(src, dst, et, cursor, sorted_se);
    k_transpose<<<(384 * D) / 256, 256, 0, stream>>>(w_ih, wihT);
    k_transpose<<<(384 * D) / 256, 256, 0, stream>>>(w_hh, whhT);

    for (int step = 0; step < N_STEPS; ++step) {
        k_edge_transform<<<dim3(N_NODES / 64, N_ETYPES), 256, 0, stream>>>(h, W_edge, b_edge, tm);
        k_gather<<<N_NODES / 4, 256, 0, stream>>>(tm, row_start, sorted_se, a);
        k_gru<<<N_NODES / 16, 256, 0, stream>>>(a, h, wihT, whhT, b_ih, b_hh);
    }

    k_readout<<<N_GRAPHS, 256, 0, stream>>>(h, w_cls, b_cls, out);
}

// Round 10
// 2513.174 us; speedup vs baseline: 1.1894x; 1.1894x over previous
//
#include <hip/hip_runtime.h>
#include <math.h>

#define N_NODES   32768
#define N_GRAPHS  64
#define NPG       512
#define N_EDGES   524288
#define D         128
#define N_ETYPES  4
#define N_STEPS   8

// ---------------------------------------------------------------------------
// Edge-type transform: tm[t][n][k] = sum_d h[n][d] * W[t][d][k]   (+bias)
// 256 threads, tile = 64 nodes x 128 cols for one etype.
// W_t staged through LDS in K-tiles of 8; 8 nodes x 4 cols per thread.
// LDS: hsT 34816 B + wl 4096 B = 38912 B -> 4 blocks/CU (155.6 KB).
// ---------------------------------------------------------------------------
#define EKT 8
__global__ __launch_bounds__(256) void k_edge_transform(
    const float* __restrict__ h, const float* __restrict__ W,
    const float* __restrict__ b, float* __restrict__ tm)
{
    __shared__ float hsT[128 * 68];      // [d][n], pad 68 (16B-aligned rows: 272B)
    __shared__ float wl[EKT * 128];      // W k-tile [dd][k]
    const int t   = blockIdx.y;
    const int n0  = blockIdx.x * 64;
    const int tid = threadIdx.x;

    #pragma unroll
    for (int it = 0; it < 32; ++it) {
        int idx = it * 256 + tid;
        int n = idx >> 7, d = idx & 127;
        hsT[d * 68 + n] = h[(size_t)(n0 + n) * D + d];
    }

    const int kq = tid & 31, k4 = kq * 4;
    const int ng = tid >> 5;
    const int nB = ng * 8;

    float acc[8][4];
    #pragma unroll
    for (int i = 0; i < 8; ++i)
        #pragma unroll
        for (int j = 0; j < 4; ++j) acc[i][j] = 0.f;

    const float* Wt = W + (size_t)t * D * D;
    for (int kt = 0; kt < D; kt += EKT) {
        __syncthreads();                 // covers hsT staging on first iter
        // stage 8x128 W slice: 256 float4 / 256 threads = 1 each
        ((float4*)wl)[tid] = ((const float4*)(Wt + (size_t)kt * D))[tid];
        __syncthreads();
        #pragma unroll
        for (int dd = 0; dd < EKT; ++dd) {
            const int d = kt + dd;
            float4 w  = *(const float4*)(&wl[dd * 128 + k4]);
            float4 h0 = *(const float4*)(&hsT[d * 68 + nB]);
            float4 h1 = *(const float4*)(&hsT[d * 68 + nB + 4]);
            float hv[8] = {h0.x, h0.y, h0.z, h0.w, h1.x, h1.y, h1.z, h1.w};
            #pragma unroll
            for (int i = 0; i < 8; ++i) {
                acc[i][0] += hv[i] * w.x;
                acc[i][1] += hv[i] * w.y;
                acc[i][2] += hv[i] * w.z;
                acc[i][3] += hv[i] * w.w;
            }
        }
    }

    float4 bias = *(const float4*)(b + t * D + k4);
    float* outp = tm + (size_t)t * N_NODES * D + (size_t)n0 * D;
    #pragma unroll
    for (int i = 0; i < 8; ++i) {
        int n = nB + i;
        float4 v = make_float4(acc[i][0] + bias.x, acc[i][1] + bias.y,
                               acc[i][2] + bias.z, acc[i][3] + bias.w);
        *(float4*)(outp + (size_t)n * D + k4) = v;
    }
}

// ---------------------------------------------------------------------------
// CSR build (once per launch): histogram -> scan -> scatter of (src|etype)
// ---------------------------------------------------------------------------
__global__ void k_hist(const int* __restrict__ dst, int* __restrict__ cnt)
{
    int e = blockIdx.x * blockDim.x + threadIdx.x;
    if (e < N_EDGES) atomicAdd(&cnt[dst[e]], 1);
}

__global__ __launch_bounds__(1024) void k_scan(
    const int* __restrict__ cnt, int* __restrict__ row_start, int* __restrict__ cursor)
{
    __shared__ int part[1024];
    const int t = threadIdx.x;
    const int base = t * 32;

    int local[32];
    int s = 0;
    #pragma unroll
    for (int j = 0; j < 32; ++j) { local[j] = cnt[base + j]; s += local[j]; }
    part[t] = s;
    __syncthreads();

    for (int off = 1; off < 1024; off <<= 1) {
        int v   = part[t];
        int add = (t >= off) ? part[t - off] : 0;
        __syncthreads();
        part[t] = v + add;
        __syncthreads();
    }
    int ex = (t == 0) ? 0 : part[t - 1];

    if (t == 0) row_start[0] = 0;
    int run = ex;
    #pragma unroll
    for (int j = 0; j < 32; ++j) {
        cursor[base + j] = run;
        run += local[j];
        row_start[base + j + 1] = run;
    }
}

__global__ void k_scatter(const int* __restrict__ src, const int* __restrict__ dst,
                          const int* __restrict__ et, int* __restrict__ cursor,
                          int* __restrict__ sorted_se)
{
    int e = blockIdx.x * blockDim.x + threadIdx.x;
    if (e < N_EDGES) {
        int p = atomicAdd(&cursor[dst[e]], 1);
        sorted_se[p] = src[e] | (et[e] << 15);
    }
}

// ---------------------------------------------------------------------------
// Gather: a[n][:] = sum over incoming edges of tm[etype][src][:]
// one 64-lane wave per node, float2 per lane
// ---------------------------------------------------------------------------
__global__ __launch_bounds__(256) void k_gather(
    const float* __restrict__ tm, const int* __restrict__ row_start,
    const int* __restrict__ sorted_se, float* __restrict__ a)
{
    const int node = blockIdx.x * 4 + (threadIdx.x >> 6);
    const int lane = threadIdx.x & 63;
    const int s0 = row_start[node], s1 = row_start[node + 1];

    float ax = 0.f, ay = 0.f;
    for (int j = s0; j < s1; ++j) {
        int se = sorted_se[j];
        int s = se & 32767, t = se >> 15;
        const float2* row = (const float2*)(tm + ((size_t)t * N_NODES + s) * D);
        float2 v = row[lane];
        ax += v.x; ay += v.y;
    }
    ((float2*)(a + (size_t)node * D))[lane] = make_float2(ax, ay);
}

// ---------------------------------------------------------------------------
// Weight transpose (once per launch): w[384][128] -> wT[128][384]
// ---------------------------------------------------------------------------
__global__ void k_transpose(const float* __restrict__ w, float* __restrict__ wT)
{
    int id = blockIdx.x * blockDim.x + threadIdx.x;
    int j = id >> 7, d = id & 127;
    wT[d * 384 + j] = w[id];
}

// ---------------------------------------------------------------------------
// Fused GRU cell: h = GRU(a, h)  (in-place, 32 nodes per block)
// r/z-fused accumulation: r,z gates only need i_g + h_g, so a- and h-matmul
// partials share one accumulator -> 64 accs/thread (was 96), same FMA count.
// Weights staged through LDS in K-tiles of 4.
// LDS: aT+hT 36864 B + wl 12288 B = 49152 B -> 3 blocks/CU (147.5 KB).
// __launch_bounds__(256,3): >=3 waves/SIMD, VGPR cap 170.
// ---------------------------------------------------------------------------
#define GKT 4
__global__ __launch_bounds__(256, 3) void k_gru(
    const float* __restrict__ a, float* __restrict__ h,
    const float* __restrict__ wihT, const float* __restrict__ whhT,
    const float* __restrict__ bih, const float* __restrict__ bhh)
{
    __shared__ float aT[128 * 36];           // [d][n], 144B rows (16B-aligned)
    __shared__ float hT[128 * 36];
    __shared__ float wl[2][GKT * 384];       // k-tile: [ih/hh][dd][j]
    const int n0  = blockIdx.x * 32;
    const int tid = threadIdx.x;

    #pragma unroll
    for (int it = 0; it < 16; ++it) {
        int idx = it * 256 + tid;
        int n = idx >> 7, d = idx & 127;
        aT[d * 36 + n] = a[(size_t)(n0 + n) * D + d];
        hT[d * 36 + n] = h[(size_t)(n0 + n) * D + d];
    }

    const int kq = tid & 31, k4 = kq * 4;
    const int ng = tid >> 5;          // 4 nodes: ng*4 .. +3
    const int nA = ng * 4;

    float grz[4][2][4];               // fused (i_r+h_r), (i_z+h_z)
    float gin[4][4], ghn[4][4];       // i_n, h_n kept separate
    {
        float4 br = *(const float4*)(bih + k4);
        float4 bz = *(const float4*)(bih + 128 + k4);
        float4 bn = *(const float4*)(bih + 256 + k4);
        float4 cr = *(const float4*)(bhh + k4);
        float4 cz = *(const float4*)(bhh + 128 + k4);
        float4 cn = *(const float4*)(bhh + 256 + k4);
        float rz0[4] = {br.x + cr.x, br.y + cr.y, br.z + cr.z, br.w + cr.w};
        float rz1[4] = {bz.x + cz.x, bz.y + cz.y, bz.z + cz.z, bz.w + cz.w};
        float inb[4] = {bn.x, bn.y, bn.z, bn.w};
        float hnb[4] = {cn.x, cn.y, cn.z, cn.w};
        #pragma unroll
        for (int i = 0; i < 4; ++i)
            #pragma unroll
            for (int j = 0; j < 4; ++j) {
                grz[i][0][j] = rz0[j];
                grz[i][1][j] = rz1[j];
                gin[i][j]    = inb[j];
                ghn[i][j]    = hnb[j];
            }
    }

    for (int kt = 0; kt < D; kt += GKT) {
        __syncthreads();                 // covers aT/hT staging on first iter
        // stage weight k-tile: 2 x 4x384 floats = 2 x 384 float4
        {
            const float4* s0 = (const float4*)(wihT + (size_t)kt * 384);
            const float4* s1 = (const float4*)(whhT + (size_t)kt * 384);
            float4* d0 = (float4*)wl[0];
            float4* d1 = (float4*)wl[1];
            d0[tid] = s0[tid];
            d1[tid] = s1[tid];
            if (tid < 128) {             // wave-uniform branch (waves 0,1)
                d0[256 + tid] = s0[256 + tid];
                d1[256 + tid] = s1[256 + tid];
            }
        }
        __syncthreads();
        #pragma unroll
        for (int dd = 0; dd < GKT; ++dd) {
            const int d = kt + dd;
            float4 av = *(const float4*)(&aT[d * 36 + nA]);   // broadcast read
            float4 hv = *(const float4*)(&hT[d * 36 + nA]);
            float avv[4] = {av.x, av.y, av.z, av.w};
            float hvv[4] = {hv.x, hv.y, hv.z, hv.w};
            float4 wir = *(const float4*)(&wl[0][dd * 384 + k4]);
            float4 wiz = *(const float4*)(&wl[0][dd * 384 + 128 + k4]);
            float4 win = *(const float4*)(&wl[0][dd * 384 + 256 + k4]);
            float4 whr = *(const float4*)(&wl[1][dd * 384 + k4]);
            float4 whz = *(const float4*)(&wl[1][dd * 384 + 128 + k4]);
            float4 whn = *(const float4*)(&wl[1][dd * 384 + 256 + k4]);
            float wirv[4] = {wir.x, wir.y, wir.z, wir.w};
            float wizv[4] = {wiz.x, wiz.y, wiz.z, wiz.w};
            float winv[4] = {win.x, win.y, win.z, win.w};
            float whrv[4] = {whr.x, whr.y, whr.z, whr.w};
            float whzv[4] = {whz.x, whz.y, whz.z, whz.w};
            float whnv[4] = {whn.x, whn.y, whn.z, whn.w};
            #pragma unroll
            for (int i = 0; i < 4; ++i)
                #pragma unroll
                for (int j = 0; j < 4; ++j) {
                    grz[i][0][j] += avv[i] * wirv[j];
                    grz[i][0][j] += hvv[i] * whrv[j];
                    grz[i][1][j] += avv[i] * wizv[j];
                    grz[i][1][j] += hvv[i] * whzv[j];
                    gin[i][j]    += avv[i] * winv[j];
                    ghn[i][j]    += hvv[i] * whnv[j];
                }
        }
    }

    #pragma unroll
    for (int i = 0; i < 4; ++i) {
        int n = n0 + nA + i;
        float hnew[4];
        #pragma unroll
        for (int j = 0; j < 4; ++j) {
            float r  = 1.f / (1.f + __expf(-grz[i][0][j]));
            float z  = 1.f / (1.f + __expf(-grz[i][1][j]));
            float nx = gin[i][j] + r * ghn[i][j];
            float nn = 2.f / (1.f + __expf(-2.f * nx)) - 1.f;   // tanh
            float ho = hT[(k4 + j) * 36 + nA + i];
            hnew[j] = (1.f - z) * nn + z * ho;
        }
        *(float4*)(h + (size_t)n * D + k4) = make_float4(hnew[0], hnew[1], hnew[2], hnew[3]);
    }
}

// ---------------------------------------------------------------------------
// Readout: out[g] = sigmoid( sum_nodes(h) . w_cls + b_cls )
// ---------------------------------------------------------------------------
__global__ __launch_bounds__(256) void k_readout(
    const float* __restrict__ h, const float* __restrict__ w_cls,
    const float* __restrict__ b_cls, float* __restrict__ out)
{
    __shared__ float sbuf[256];
    const int g = blockIdx.x;
    const int tid = threadIdx.x;
    const int k = tid & 127, half = tid >> 7;

    float s = 0.f;
    for (int r = half; r < NPG; r += 2)
        s += h[((size_t)g * NPG + r) * D + k];
    sbuf[tid] = s;
    __syncthreads();

    if (tid < 64) {
        int l = tid;
        float v = (sbuf[l]      + sbuf[l + 128]) * w_cls[l]
                + (sbuf[l + 64] + sbuf[l + 192]) * w_cls[l + 64];
        #pragma unroll
        for (int off = 32; off > 0; off >>= 1) v += __shfl_down(v, off);
        if (l == 0) out[g] = 1.f / (1.f + __expf(-(v + b_cls[0])));
    }
}

// ---------------------------------------------------------------------------
extern "C" void kernel_launch(void* const* d_in, const int* in_sizes, int n_in,
                              void* d_out, int out_size, void* d_ws, size_t ws_size,
                              hipStream_t stream)
{
    const float* feat   = (const float*)d_in[0];
    const float* W_edge = (const float*)d_in[1];
    const float* b_edge = (const float*)d_in[2];
    const float* w_ih   = (const float*)d_in[3];
    const float* w_hh   = (const float*)d_in[4];
    const float* b_ih   = (const float*)d_in[5];
    const float* b_hh   = (const float*)d_in[6];
    const float* w_cls  = (const float*)d_in[7];
    const float* b_cls  = (const float*)d_in[8];
    const int*   src    = (const int*)d_in[9];
    const int*   dst    = (const int*)d_in[10];
    const int*   et     = (const int*)d_in[11];
    float* out = (float*)d_out;

    char* ws = (char*)d_ws;
    size_t off = 0;
    auto alloc = [&](size_t bytes) -> void* {
        void* p = ws + off;
        off += (bytes + 255) & ~(size_t)255;
        return p;
    };

    float* h         = (float*)alloc((size_t)N_NODES * D * 4);
    float* a         = (float*)alloc((size_t)N_NODES * D * 4);
    float* tm        = (float*)alloc((size_t)N_ETYPES * N_NODES * D * 4);
    int*   cnt       = (int*)alloc((size_t)N_NODES * 4);
    int*   cursor    = (int*)alloc((size_t)N_NODES * 4);
    int*   row_start = (int*)alloc((size_t)(N_NODES + 1) * 4);
    int*   sorted_se = (int*)alloc((size_t)N_EDGES * 4);
    float* wihT      = (float*)alloc((size_t)384 * D * 4);
    float* whhT      = (float*)alloc((size_t)384 * D * 4);

    hipMemcpyAsync(h, feat, (size_t)N_NODES * D * 4, hipMemcpyDeviceToDevice, stream);

    hipMemsetAsync(cnt, 0, (size_t)N_NODES * 4, stream);
    k_hist<<<N_EDGES / 256, 256, 0, stream>>>(dst, cnt);
    k_scan<<<1, 1024, 0, stream>>>(cnt, row_start, cursor);
    k_scatter<<<N_EDGES / 256, 256, 0, stream>>>(src, dst, et, cursor, sorted_se);
    k_transpose<<<(384 * D) / 256, 256, 0, stream>>>(w_ih, wihT);
    k_transpose<<<(384 * D) / 256, 256, 0, stream>>>(w_hh, whhT);

    for (int step = 0; step < N_STEPS; ++step) {
        k_edge_transform<<<dim3(N_NODES / 64, N_ETYPES), 256, 0, stream>>>(h, W_edge, b_edge, tm);
        k_gather<<<N_NODES / 4, 256, 0, stream>>>(tm, row_start, sorted_se, a);
        k_gru<<<N_NODES / 16, 256, 0, stream>>>(a, h, wihT, whhT, b_ih, b_hh);
    }

    k_readout<<<N_GRAPHS, 256, 0, stream>>>(h, w_cls, b_cls, out);
}

// Round 12
// 1947.990 us; speedup vs baseline: 1.5345x; 1.2901x over previous
//
#include <hip/hip_runtime.h>
#include <math.h>

#define N_NODES   32768
#define N_GRAPHS  64
#define NPG       512
#define N_EDGES   524288
#define D         128
#define N_ETYPES  4
#define N_STEPS   8

// ---------------------------------------------------------------------------
// Edge-type transform: tm[t][n][k] = sum_d h[n][d] * W[t][d][k]   (+bias)
// 256 threads, tile = 64 nodes x 128 cols for one etype.
// W_t staged through LDS in K-tiles of 8; 8 nodes x 4 cols per thread.
// LDS: hsT 34816 B + wl 4096 B = 38912 B -> 4 blocks/CU (155.6 KB).
// ---------------------------------------------------------------------------
#define EKT 8
__global__ __launch_bounds__(256) void k_edge_transform(
    const float* __restrict__ h, const float* __restrict__ W,
    const float* __restrict__ b, float* __restrict__ tm)
{
    __shared__ float hsT[128 * 68];      // [d][n], pad 68 (16B-aligned rows: 272B)
    __shared__ float wl[EKT * 128];      // W k-tile [dd][k]
    const int t   = blockIdx.y;
    const int n0  = blockIdx.x * 64;
    const int tid = threadIdx.x;

    #pragma unroll
    for (int it = 0; it < 32; ++it) {
        int idx = it * 256 + tid;
        int n = idx >> 7, d = idx & 127;
        hsT[d * 68 + n] = h[(size_t)(n0 + n) * D + d];
    }

    const int kq = tid & 31, k4 = kq * 4;
    const int ng = tid >> 5;
    const int nB = ng * 8;

    float acc[8][4];
    #pragma unroll
    for (int i = 0; i < 8; ++i)
        #pragma unroll
        for (int j = 0; j < 4; ++j) acc[i][j] = 0.f;

    const float* Wt = W + (size_t)t * D * D;
    for (int kt = 0; kt < D; kt += EKT) {
        __syncthreads();                 // covers hsT staging on first iter
        // stage 8x128 W slice: 256 float4 / 256 threads = 1 each
        ((float4*)wl)[tid] = ((const float4*)(Wt + (size_t)kt * D))[tid];
        __syncthreads();
        #pragma unroll
        for (int dd = 0; dd < EKT; ++dd) {
            const int d = kt + dd;
            float4 w  = *(const float4*)(&wl[dd * 128 + k4]);
            float4 h0 = *(const float4*)(&hsT[d * 68 + nB]);
            float4 h1 = *(const float4*)(&hsT[d * 68 + nB + 4]);
            float hv[8] = {h0.x, h0.y, h0.z, h0.w, h1.x, h1.y, h1.z, h1.w};
            #pragma unroll
            for (int i = 0; i < 8; ++i) {
                acc[i][0] += hv[i] * w.x;
                acc[i][1] += hv[i] * w.y;
                acc[i][2] += hv[i] * w.z;
                acc[i][3] += hv[i] * w.w;
            }
        }
    }

    float4 bias = *(const float4*)(b + t * D + k4);
    float* outp = tm + (size_t)t * N_NODES * D + (size_t)n0 * D;
    #pragma unroll
    for (int i = 0; i < 8; ++i) {
        int n = nB + i;
        float4 v = make_float4(acc[i][0] + bias.x, acc[i][1] + bias.y,
                               acc[i][2] + bias.z, acc[i][3] + bias.w);
        *(float4*)(outp + (size_t)n * D + k4) = v;
    }
}

// ---------------------------------------------------------------------------
// CSR build (once per launch): histogram -> scan -> scatter of (src|etype)
// ---------------------------------------------------------------------------
__global__ void k_hist(const int* __restrict__ dst, int* __restrict__ cnt)
{
    int e = blockIdx.x * blockDim.x + threadIdx.x;
    if (e < N_EDGES) atomicAdd(&cnt[dst[e]], 1);
}

__global__ __launch_bounds__(1024) void k_scan(
    const int* __restrict__ cnt, int* __restrict__ row_start, int* __restrict__ cursor)
{
    __shared__ int part[1024];
    const int t = threadIdx.x;
    const int base = t * 32;

    int local[32];
    int s = 0;
    #pragma unroll
    for (int j = 0; j < 32; ++j) { local[j] = cnt[base + j]; s += local[j]; }
    part[t] = s;
    __syncthreads();

    for (int off = 1; off < 1024; off <<= 1) {
        int v   = part[t];
        int add = (t >= off) ? part[t - off] : 0;
        __syncthreads();
        part[t] = v + add;
        __syncthreads();
    }
    int ex = (t == 0) ? 0 : part[t - 1];

    if (t == 0) row_start[0] = 0;
    int run = ex;
    #pragma unroll
    for (int j = 0; j < 32; ++j) {
        cursor[base + j] = run;
        run += local[j];
        row_start[base + j + 1] = run;
    }
}

__global__ void k_scatter(const int* __restrict__ src, const int* __restrict__ dst,
                          const int* __restrict__ et, int* __restrict__ cursor,
                          int* __restrict__ sorted_se)
{
    int e = blockIdx.x * blockDim.x + threadIdx.x;
    if (e < N_EDGES) {
        int p = atomicAdd(&cursor[dst[e]], 1);
        sorted_se[p] = src[e] | (et[e] << 15);
    }
}

// ---------------------------------------------------------------------------
// Gather: a[n][:] = sum over incoming edges of tm[etype][src][:]
// one 64-lane wave per node, float2 per lane
// ---------------------------------------------------------------------------
__global__ __launch_bounds__(256) void k_gather(
    const float* __restrict__ tm, const int* __restrict__ row_start,
    const int* __restrict__ sorted_se, float* __restrict__ a)
{
    const int node = blockIdx.x * 4 + (threadIdx.x >> 6);
    const int lane = threadIdx.x & 63;
    const int s0 = row_start[node], s1 = row_start[node + 1];

    float ax = 0.f, ay = 0.f;
    for (int j = s0; j < s1; ++j) {
        int se = sorted_se[j];
        int s = se & 32767, t = se >> 15;
        const float2* row = (const float2*)(tm + ((size_t)t * N_NODES + s) * D);
        float2 v = row[lane];
        ax += v.x; ay += v.y;
    }
    ((float2*)(a + (size_t)node * D))[lane] = make_float2(ax, ay);
}

// ---------------------------------------------------------------------------
// Weight transpose (once per launch): w[384][128] -> wT[128][384]
// ---------------------------------------------------------------------------
__global__ void k_transpose(const float* __restrict__ w, float* __restrict__ wT)
{
    int id = blockIdx.x * blockDim.x + threadIdx.x;
    int j = id >> 7, d = id & 127;
    wT[d * 384 + j] = w[id];
}

// ---------------------------------------------------------------------------
// Fused GRU cell: h = GRU(a, h)  (in-place, 32 nodes per block)
// r/z-fused accumulation -> 64 accs/thread; weights LDS-staged in K-tiles of 4.
// LDS: aT+hT 36864 B + wl 12288 B = 49152 B -> 3 blocks/CU.
// GRID: N_NODES/32 = 1024 blocks (32 nodes per block). [R10 bug: was /16,
// which ran a full redundant second pass on phantom nodes 32768..65535]
// ---------------------------------------------------------------------------
#define GKT 4
__global__ __launch_bounds__(256, 3) void k_gru(
    const float* __restrict__ a, float* __restrict__ h,
    const float* __restrict__ wihT, const float* __restrict__ whhT,
    const float* __restrict__ bih, const float* __restrict__ bhh)
{
    __shared__ float aT[128 * 36];           // [d][n], 144B rows (16B-aligned)
    __shared__ float hT[128 * 36];
    __shared__ float wl[2][GKT * 384];       // k-tile: [ih/hh][dd][j]
    const int n0  = blockIdx.x * 32;
    const int tid = threadIdx.x;

    #pragma unroll
    for (int it = 0; it < 16; ++it) {
        int idx = it * 256 + tid;
        int n = idx >> 7, d = idx & 127;
        aT[d * 36 + n] = a[(size_t)(n0 + n) * D + d];
        hT[d * 36 + n] = h[(size_t)(n0 + n) * D + d];
    }

    const int kq = tid & 31, k4 = kq * 4;
    const int ng = tid >> 5;          // 4 nodes: ng*4 .. +3
    const int nA = ng * 4;

    float grz[4][2][4];               // fused (i_r+h_r), (i_z+h_z)
    float gin[4][4], ghn[4][4];       // i_n, h_n kept separate
    {
        float4 br = *(const float4*)(bih + k4);
        float4 bz = *(const float4*)(bih + 128 + k4);
        float4 bn = *(const float4*)(bih + 256 + k4);
        float4 cr = *(const float4*)(bhh + k4);
        float4 cz = *(const float4*)(bhh + 128 + k4);
        float4 cn = *(const float4*)(bhh + 256 + k4);
        float rz0[4] = {br.x + cr.x, br.y + cr.y, br.z + cr.z, br.w + cr.w};
        float rz1[4] = {bz.x + cz.x, bz.y + cz.y, bz.z + cz.z, bz.w + cz.w};
        float inb[4] = {bn.x, bn.y, bn.z, bn.w};
        float hnb[4] = {cn.x, cn.y, cn.z, cn.w};
        #pragma unroll
        for (int i = 0; i < 4; ++i)
            #pragma unroll
            for (int j = 0; j < 4; ++j) {
                grz[i][0][j] = rz0[j];
                grz[i][1][j] = rz1[j];
                gin[i][j]    = inb[j];
                ghn[i][j]    = hnb[j];
            }
    }

    for (int kt = 0; kt < D; kt += GKT) {
        __syncthreads();                 // covers aT/hT staging on first iter
        // stage weight k-tile: 2 x 4x384 floats = 2 x 384 float4
        {
            const float4* s0 = (const float4*)(wihT + (size_t)kt * 384);
            const float4* s1 = (const float4*)(whhT + (size_t)kt * 384);
            float4* d0 = (float4*)wl[0];
            float4* d1 = (float4*)wl[1];
            d0[tid] = s0[tid];
            d1[tid] = s1[tid];
            if (tid < 128) {             // wave-uniform branch (waves 0,1)
                d0[256 + tid] = s0[256 + tid];
                d1[256 + tid] = s1[256 + tid];
            }
        }
        __syncthreads();
        #pragma unroll
        for (int dd = 0; dd < GKT; ++dd) {
            const int d = kt + dd;
            float4 av = *(const float4*)(&aT[d * 36 + nA]);   // broadcast read
            float4 hv = *(const float4*)(&hT[d * 36 + nA]);
            float avv[4] = {av.x, av.y, av.z, av.w};
            float hvv[4] = {hv.x, hv.y, hv.z, hv.w};
            float4 wir = *(const float4*)(&wl[0][dd * 384 + k4]);
            float4 wiz = *(const float4*)(&wl[0][dd * 384 + 128 + k4]);
            float4 win = *(const float4*)(&wl[0][dd * 384 + 256 + k4]);
            float4 whr = *(const float4*)(&wl[1][dd * 384 + k4]);
            float4 whz = *(const float4*)(&wl[1][dd * 384 + 128 + k4]);
            float4 whn = *(const float4*)(&wl[1][dd * 384 + 256 + k4]);
            float wirv[4] = {wir.x, wir.y, wir.z, wir.w};
            float wizv[4] = {wiz.x, wiz.y, wiz.z, wiz.w};
            float winv[4] = {win.x, win.y, win.z, win.w};
            float whrv[4] = {whr.x, whr.y, whr.z, whr.w};
            float whzv[4] = {whz.x, whz.y, whz.z, whz.w};
            float whnv[4] = {whn.x, whn.y, whn.z, whn.w};
            #pragma unroll
            for (int i = 0; i < 4; ++i)
                #pragma unroll
                for (int j = 0; j < 4; ++j) {
                    grz[i][0][j] += avv[i] * wirv[j];
                    grz[i][0][j] += hvv[i] * whrv[j];
                    grz[i][1][j] += avv[i] * wizv[j];
                    grz[i][1][j] += hvv[i] * whzv[j];
                    gin[i][j]    += avv[i] * winv[j];
                    ghn[i][j]    += hvv[i] * whnv[j];
                }
        }
    }

    #pragma unroll
    for (int i = 0; i < 4; ++i) {
        int n = n0 + nA + i;
        float hnew[4];
        #pragma unroll
        for (int j = 0; j < 4; ++j) {
            float r  = 1.f / (1.f + __expf(-grz[i][0][j]));
            float z  = 1.f / (1.f + __expf(-grz[i][1][j]));
            float nx = gin[i][j] + r * ghn[i][j];
            float nn = 2.f / (1.f + __expf(-2.f * nx)) - 1.f;   // tanh
            float ho = hT[(k4 + j) * 36 + nA + i];
            hnew[j] = (1.f - z) * nn + z * ho;
        }
        *(float4*)(h + (size_t)n * D + k4) = make_float4(hnew[0], hnew[1], hnew[2], hnew[3]);
    }
}

// ---------------------------------------------------------------------------
// Readout: out[g] = sigmoid( sum_nodes(h) . w_cls + b_cls )
// ---------------------------------------------------------------------------
__global__ __launch_bounds__(256) void k_readout(
    const float* __restrict__ h, const float* __restrict__ w_cls,
    const float* __restrict__ b_cls, float* __restrict__ out)
{
    __shared__ float sbuf[256];
    const int g = blockIdx.x;
    const int tid = threadIdx.x;
    const int k = tid & 127, half = tid >> 7;

    float s = 0.f;
    for (int r = half; r < NPG; r += 2)
        s += h[((size_t)g * NPG + r) * D + k];
    sbuf[tid] = s;
    __syncthreads();

    if (tid < 64) {
        int l = tid;
        float v = (sbuf[l]      + sbuf[l + 128]) * w_cls[l]
                + (sbuf[l + 64] + sbuf[l + 192]) * w_cls[l + 64];
        #pragma unroll
        for (int off = 32; off > 0; off >>= 1) v += __shfl_down(v, off);
        if (l == 0) out[g] = 1.f / (1.f + __expf(-(v + b_cls[0])));
    }
}

// ---------------------------------------------------------------------------
extern "C" void kernel_launch(void* const* d_in, const int* in_sizes, int n_in,
                              void* d_out, int out_size, void* d_ws, size_t ws_size,
                              hipStream_t stream)
{
    const float* feat   = (const float*)d_in[0];
    const float* W_edge = (const float*)d_in[1];
    const float* b_edge = (const float*)d_in[2];
    const float* w_ih   = (const float*)d_in[3];
    const float* w_hh   = (const float*)d_in[4];
    const float* b_ih   = (const float*)d_in[5];
    const float* b_hh   = (const float*)d_in[6];
    const float* w_cls  = (const float*)d_in[7];
    const float* b_cls  = (const float*)d_in[8];
    const int*   src    = (const int*)d_in[9];
    const int*   dst    = (const int*)d_in[10];
    const int*   et     = (const int*)d_in[11];
    float* out = (float*)d_out;

    char* ws = (char*)d_ws;
    size_t off = 0;
    auto alloc = [&](size_t bytes) -> void* {
        void* p = ws + off;
        off += (bytes + 255) & ~(size_t)255;
        return p;
    };

    float* h         = (float*)alloc((size_t)N_NODES * D * 4);
    float* a         = (float*)alloc((size_t)N_NODES * D * 4);
    float* tm        = (float*)alloc((size_t)N_ETYPES * N_NODES * D * 4);
    int*   cnt       = (int*)alloc((size_t)N_NODES * 4);
    int*   cursor    = (int*)alloc((size_t)N_NODES * 4);
    int*   row_start = (int*)alloc((size_t)(N_NODES + 1) * 4);
    int*   sorted_se = (int*)alloc((size_t)N_EDGES * 4);
    float* wihT      = (float*)alloc((size_t)384 * D * 4);
    float* whhT      = (float*)alloc((size_t)384 * D * 4);

    hipMemcpyAsync(h, feat, (size_t)N_NODES * D * 4, hipMemcpyDeviceToDevice, stream);

    hipMemsetAsync(cnt, 0, (size_t)N_NODES * 4, stream);
    k_hist<<<N_EDGES / 256, 256, 0, stream>>>(dst, cnt);
    k_scan<<<1, 1024, 0, stream>>>(cnt, row_start, cursor);
    k_scatter<<<N_EDGES / 256, 256, 0, stream>>>(src, dst, et, cursor, sorted_se);
    k_transpose<<<(384 * D) / 256, 256, 0, stream>>>(w_ih, wihT);
    k_transpose<<<(384 * D) / 256, 256, 0, stream>>>(w_hh, whhT);

    for (int step = 0; step < N_STEPS; ++step) {
        k_edge_transform<<<dim3(N_NODES / 64, N_ETYPES), 256, 0, stream>>>(h, W_edge, b_edge, tm);
        k_gather<<<N_NODES / 4, 256, 0, stream>>>(tm, row_start, sorted_se, a);
        k_gru<<<N_NODES / 32, 256, 0, stream>>>(a, h, wihT, whhT, b_ih, b_hh);
    }

    k_readout<<<N_GRAPHS, 256, 0, stream>>>(h, w_cls, b_cls, out);
}